// Round 1
// 149.934 us; speedup vs baseline: 1.1162x; 1.1162x over previous
//
#include <hip/hip_runtime.h>

typedef _Float16 half8 __attribute__((ext_vector_type(8)));
typedef float f32x4 __attribute__((ext_vector_type(4)));

#define SPH  32           // timesteps per phase
#define NIT  34           // 32 compute phases + 2 pipeline-drain iterations
#define SPKW 392          // spk row stride f16: 384 + 8 pad (784 B rows)
#define XTW  36           // xsT row stride (floats): 144 B rows, 16B-aligned cols
#define C2W  48           // c2L row stride (floats)
#define TN   1000

// R12: attack conv-side LDS instruction issue. R11 counters: all pipes <40%,
// phase = ~7.4k cyc, but conv waves issue 1536 wave-LDS-insts/phase (7x b32
// read + 1x b16 write per neuron-step) of ~1650 total -- LDS-issue bound.
// Change: x tile staged TRANSPOSED as xsT[l][s] (rows 144 B). Conv thread
// processes 4 timesteps/iter with 7x ds_read_b128 (one vaddr + imm offsets
// k*144+s0*4), cutting conv LDS insts ~3x and the address VALU with it.
// Wave layout unchanged from R11:
//   waves 0-5  (384 thr): conv+LIF1(ph), ONE neuron/thread (c=ct/24, p=ct%24)
//   waves 6-11 (384 thr): FC GEMM(ph-1); also stage xsT(ph+1)
//   wave 6:    LIF2 scan(ph-2)
// One barrier per iteration; producer->consumer 1 barrier apart.
__global__ __launch_bounds__(768, 1) void snn_fwd(
    const float* __restrict__ x,      // (256,1000,30)
    const float* __restrict__ conv_w, // (16,1,7)
    const float* __restrict__ conv_b, // (16)
    const float* __restrict__ fc_w,   // (35,384)
    const float* __restrict__ fc_b,   // (35)
    float* __restrict__ out)          // (256,35)
{
    __shared__ __align__(16) _Float16 spk[2][SPH][SPKW];   // 50176 B
    __shared__ __align__(16) float    xsT[2][30][XTW];     //  8640 B
    __shared__ __align__(16) float    c2L[2][SPH][C2W];    // 12288 B

    const int tid  = threadIdx.x;
    const int b    = blockIdx.x;
    const int wid  = tid >> 6;
    const int lane = tid & 63;

    // ---------- conv setup (wid<6): thread = (c=ct/24, p=ct%24), ONE neuron ----------
    const int ct = tid;              // 0..383 when wid<6
    const int c  = ct / 24;
    const int p  = ct % 24;
    float wk[7];
    float cb = 0.f;
    if (wid < 6) {
#pragma unroll
        for (int k = 0; k < 7; ++k) wk[k] = conv_w[c * 7 + k];
        cb = conv_b[c];
    }

    // ---------- FC setup (wid>=6): g=(wid-6): m=g>>1 (M-tile), tb=g&1 (t-block) ----------
    const int g  = wid - 6;
    const int m  = g >> 1;
    const int tb = g & 1;
    const int nL = lane & 15;        // B col (t_local); C col
    const int q  = lane >> 4;        // quad: k = q*8 + j
    half8 A[12];
    if (wid >= 6) {
        const int o = m * 16 + nL;
#pragma unroll
        for (int kt = 0; kt < 12; ++kt) {
            half8 a;
#pragma unroll
            for (int j = 0; j < 8; ++j) {
                int K = kt * 32 + q * 8 + j;
                a[j] = (o < 35) ? (_Float16)fc_w[o * 384 + K] : (_Float16)0.f;
            }
            A[kt] = a;
        }
    }
    const float fcb = (wid == 6 && lane < 35) ? fc_b[lane] : 0.f;
    const int st = tid - 384;        // staging index 0..383 for wid>=6

    // ---------- state ----------
    float m1 = 0.f, sp = 0.f;        // LIF1 (one neuron)
    float mem2 = 0.f, accO = 0.f;    // LIF2 (wave6 lanes<35)

    const float* xb = x + (size_t)b * (TN * 30);

    // ---------- prologue: stage xsT[0] (960 floats; wid>=6, 3 strided each) ----------
    if (wid >= 6) {
#pragma unroll
        for (int r = 0; r < 3; ++r) {
            int f = st + 384 * r;        // 0..1151
            if (f < 960) xsT[0][f % 30][f / 30] = xb[f];   // t < 32 < TN
        }
    }
    __syncthreads();

#pragma unroll 1
    for (int ph = 0; ph < NIT; ++ph) {
        if (wid < 6) {
            // =================== conv+LIF1(ph): 4 timesteps per iter ===================
            if (ph < 32) {
                const float* xcol = &xsT[ph & 1][p][0];
                unsigned short* sdst = (unsigned short*)&spk[ph & 1][0][ct];
#pragma unroll 2
                for (int s0 = 0; s0 < SPH; s0 += 4) {
                    f32x4 xv[7];
#pragma unroll
                    for (int k = 0; k < 7; ++k)
                        xv[k] = *(const f32x4*)(xcol + k * XTW + s0);
                    float cc[4];
#pragma unroll
                    for (int dt = 0; dt < 4; ++dt) cc[dt] = cb;
#pragma unroll
                    for (int k = 0; k < 7; ++k) {
#pragma unroll
                        for (int dt = 0; dt < 4; ++dt)
                            cc[dt] = fmaf(wk[k], xv[k][dt], cc[dt]);
                    }
#pragma unroll
                    for (int dt = 0; dt < 4; ++dt) {
                        m1 = fmaf(0.9f, m1, cc[dt] - sp);
                        sp = (m1 > 1.0f) ? 1.0f : 0.0f;
                        sdst[(s0 + dt) * SPKW] =
                            (m1 > 1.0f) ? (unsigned short)0x3C00u : (unsigned short)0u;
                    }
                }
            }
        } else {
            // ====== staging loads for ph+1 issued first (latency overlap) ======
            float xr[3];
            const bool stg = (ph <= 30);
            if (stg) {
                const float* src = xb + (ph + 1) * (SPH * 30);
#pragma unroll
                for (int r = 0; r < 3; ++r) {
                    int f = st + 384 * r;
                    int t = (ph + 1) * SPH + f / 30;
                    xr[r] = (f < 960 && t < TN) ? src[f] : 0.f;
                }
            }
            // ---- scan loads hoisted before MFMA (wave 6 only) ----
            const bool doScan = (wid == 6 && lane < 35 && ph >= 2);
            float v[SPH];
            if (doScan) {
                const float* cs = &c2L[(ph - 2) & 1][0][0];
#pragma unroll
                for (int j = 0; j < SPH; ++j) v[j] = cs[j * C2W + lane];
            }
            // =================== GEMM(ph-1): this wave's (m, tb) ===================
            if (ph >= 1 && ph <= 32) {
                const _Float16* sb = &spk[(ph - 1) & 1][0][0];
                half8 B[12];
#pragma unroll
                for (int kt = 0; kt < 12; ++kt)
                    B[kt] = *(const half8*)(sb + (tb * 16 + nL) * SPKW + kt * 32 + q * 8);
                f32x4 acc = {0.f, 0.f, 0.f, 0.f};
#pragma unroll
                for (int kt = 0; kt < 12; ++kt)
                    acc = __builtin_amdgcn_mfma_f32_16x16x32_f16(A[kt], B[kt], acc, 0, 0, 0);
                // C/D: col = lane&15 (t_local), row = q*4+i (o_local)
                float* cd = &c2L[(ph - 1) & 1][0][0];
                *(f32x4*)(cd + (tb * 16 + nL) * C2W + m * 16 + q * 4) = acc;
            }
            // =================== LIF2 scan(ph-2) (wave 6 lanes<35) ===================
            if (doScan) {
                const int tbase = (ph - 2) * SPH;
#pragma unroll
                for (int j = 0; j < SPH; ++j) {
                    float r2 = (mem2 > 1.0f) ? 1.0f : 0.0f;
                    mem2 = 0.9f * mem2 + (v[j] + fcb) - r2;
                    if (tbase + j < TN) accO += mem2;
                }
            }
            // ====== staging stores for ph+1 (transposed; after everything else) ======
            if (stg) {
                float* dst = &xsT[(ph + 1) & 1][0][0];
#pragma unroll
                for (int r = 0; r < 3; ++r) {
                    int f = st + 384 * r;
                    if (f < 960) dst[(f % 30) * XTW + (f / 30)] = xr[r];
                }
            }
        }
        __syncthreads();
    }

    if (wid == 6 && lane < 35) out[b * 35 + lane] = accO * (1.0f / (float)TN);
}

extern "C" void kernel_launch(void* const* d_in, const int* in_sizes, int n_in,
                              void* d_out, int out_size, void* d_ws, size_t ws_size,
                              hipStream_t stream) {
    const float* x      = (const float*)d_in[0];
    const float* conv_w = (const float*)d_in[1];
    const float* conv_b = (const float*)d_in[2];
    const float* fc_w   = (const float*)d_in[3];
    const float* fc_b   = (const float*)d_in[4];
    float* out          = (float*)d_out;

    snn_fwd<<<256, 768, 0, stream>>>(x, conv_w, conv_b, fc_w, fc_b, out);
}

// Round 2
// 146.973 us; speedup vs baseline: 1.1387x; 1.0201x over previous
//
#include <hip/hip_runtime.h>

typedef _Float16 half8 __attribute__((ext_vector_type(8)));
typedef float f32x4 __attribute__((ext_vector_type(4)));

#define SPH  32           // timesteps per phase
#define NIT  34           // 32 compute phases + 2 pipeline-drain iterations
#define SPKW 392          // spk row stride f16: 384 + 8 pad (784 B rows)
#define XTW  36           // xsT row stride (floats): 144 B rows, 16B-aligned cols
#define C2W  48           // c2L row stride (floats)
#define TN   1000

// R13: TLP + staging deep-pipeline. R12 counters: all pipes <45%, phase 6.2k
// cyc; VALUBusy 43% => each SIMD issues ~2.7k cyc, rest is unfillable stall at
// 3 waves/SIMD. R12 post-mortem validated "phase ~ issue + stalls" (conv LDS
// cut of ~1.2k insts removed ~1.2k cyc). This round: 1024 thr = 16 waves
// (4/SIMD), and staging loads issued a FULL phase before their vmcnt-wait.
//   waves 0-5  (384 thr): conv+LIF1(ph), ONE neuron/thread (unchanged)
//   waves 6-11 (384 thr): FC GEMM(ph-1) ONLY (12 B-loads + 12 MFMA + store)
//   waves 12-15(256 thr): stage xsT: store(ph+1 data, loaded last phase) at
//                         top, then issue loads(ph+2 data); wave 12: LIF2
//                         scan(ph-2) + final output.
// One barrier per iteration; producer->consumer 1 barrier apart.
__global__ __launch_bounds__(1024, 4) void snn_fwd(
    const float* __restrict__ x,      // (256,1000,30)
    const float* __restrict__ conv_w, // (16,1,7)
    const float* __restrict__ conv_b, // (16)
    const float* __restrict__ fc_w,   // (35,384)
    const float* __restrict__ fc_b,   // (35)
    float* __restrict__ out)          // (256,35)
{
    __shared__ __align__(16) _Float16 spk[2][SPH][SPKW];   // 50176 B
    __shared__ __align__(16) float    xsT[2][30][XTW];     //  8640 B
    __shared__ __align__(16) float    c2L[2][SPH][C2W];    // 12288 B

    const int tid  = threadIdx.x;
    const int b    = blockIdx.x;
    const int wid  = tid >> 6;
    const int lane = tid & 63;

    // ---------- conv setup (wid<6): thread = (c=ct/24, p=ct%24), ONE neuron ----------
    const int ct = tid;              // 0..383 when wid<6
    const int c  = ct / 24;
    const int p  = ct % 24;
    float wk[7];
    float cb = 0.f;
    if (wid < 6) {
#pragma unroll
        for (int k = 0; k < 7; ++k) wk[k] = conv_w[c * 7 + k];
        cb = conv_b[c];
    }

    // ---------- FC setup (wid 6..11): g=(wid-6): m=g>>1 (M-tile), tb=g&1 ----------
    const int g  = wid - 6;
    const int m  = g >> 1;
    const int tb = g & 1;
    const int nL = lane & 15;        // B col (t_local); C col
    const int q  = lane >> 4;        // quad: k = q*8 + j
    half8 A[12];
    if (wid >= 6 && wid < 12) {
        const int o = m * 16 + nL;
#pragma unroll
        for (int kt = 0; kt < 12; ++kt) {
            half8 a;
#pragma unroll
            for (int j = 0; j < 8; ++j) {
                int K = kt * 32 + q * 8 + j;
                a[j] = (o < 35) ? (_Float16)fc_w[o * 384 + K] : (_Float16)0.f;
            }
            A[kt] = a;
        }
    }

    // ---------- stage/scan setup (wid>=12) ----------
    const int st4 = tid - 768;       // 0..255
    int fs[4], fl[4];                // f = st4+256r -> s=f/30, l=f%30 (hoisted)
    if (wid >= 12) {
#pragma unroll
        for (int r = 0; r < 4; ++r) {
            int f = st4 + 256 * r;   // 0..1023
            fs[r] = f / 30;
            fl[r] = f % 30;
        }
    }
    const float fcb = (wid == 12 && lane < 35) ? fc_b[lane] : 0.f;

    // ---------- state ----------
    float m1 = 0.f, sp = 0.f;        // LIF1 (one neuron)
    float mem2 = 0.f, accO = 0.f;    // LIF2 (wave12 lanes<35)
    float xr[4];                     // staging regs (wid>=12), data phase ph+1

    const float* xb = x + (size_t)b * (TN * 30);

    // ---------- prologue (wid>=12): stage xsT[0]; issue loads for data phase 1 ----------
    if (wid >= 12) {
#pragma unroll
        for (int r = 0; r < 4; ++r) {
            int f = st4 + 256 * r;
            if (f < 960) xsT[0][fl[r]][fs[r]] = xb[f];     // t < 32 < TN
        }
#pragma unroll
        for (int r = 0; r < 4; ++r) {
            int f = st4 + 256 * r;
            xr[r] = (f < 960) ? xb[960 + f] : 0.f;         // t < 64 < TN
        }
    }
    __syncthreads();

#pragma unroll 1
    for (int ph = 0; ph < NIT; ++ph) {
        if (wid < 6) {
            // =================== conv+LIF1(ph): 4 timesteps per iter ===================
            if (ph < 32) {
                const float* xcol = &xsT[ph & 1][p][0];
                unsigned short* sdst = (unsigned short*)&spk[ph & 1][0][ct];
#pragma unroll 2
                for (int s0 = 0; s0 < SPH; s0 += 4) {
                    f32x4 xv[7];
#pragma unroll
                    for (int k = 0; k < 7; ++k)
                        xv[k] = *(const f32x4*)(xcol + k * XTW + s0);
                    float cc[4];
#pragma unroll
                    for (int dt = 0; dt < 4; ++dt) cc[dt] = cb;
#pragma unroll
                    for (int k = 0; k < 7; ++k) {
#pragma unroll
                        for (int dt = 0; dt < 4; ++dt)
                            cc[dt] = fmaf(wk[k], xv[k][dt], cc[dt]);
                    }
#pragma unroll
                    for (int dt = 0; dt < 4; ++dt) {
                        m1 = fmaf(0.9f, m1, cc[dt] - sp);
                        sp = (m1 > 1.0f) ? 1.0f : 0.0f;
                        sdst[(s0 + dt) * SPKW] =
                            (m1 > 1.0f) ? (unsigned short)0x3C00u : (unsigned short)0u;
                    }
                }
            }
        } else if (wid < 12) {
            // =================== GEMM(ph-1): this wave's (m, tb) ===================
            if (ph >= 1 && ph <= 32) {
                const _Float16* sb = &spk[(ph - 1) & 1][0][0];
                half8 B[12];
#pragma unroll
                for (int kt = 0; kt < 12; ++kt)
                    B[kt] = *(const half8*)(sb + (tb * 16 + nL) * SPKW + kt * 32 + q * 8);
                f32x4 acc = {0.f, 0.f, 0.f, 0.f};
#pragma unroll
                for (int kt = 0; kt < 12; ++kt)
                    acc = __builtin_amdgcn_mfma_f32_16x16x32_f16(A[kt], B[kt], acc, 0, 0, 0);
                // C/D: col = lane&15 (t_local), row = q*4+i (o_local)
                float* cd = &c2L[(ph - 1) & 1][0][0];
                *(f32x4*)(cd + (tb * 16 + nL) * C2W + m * 16 + q * 4) = acc;
            }
        } else {
            // ====== staging store (data ph+1, loaded a full phase ago) ======
            // Writes buffer (ph+1)&1; conv is reading (ph)&1 -> no race.
            if (ph <= 30) {
                float* dst = &xsT[(ph + 1) & 1][0][0];
#pragma unroll
                for (int r = 0; r < 4; ++r) {
                    int f = st4 + 256 * r;
                    if (f < 960) dst[fl[r] * XTW + fs[r]] = xr[r];
                }
            }
            // ====== staging loads for data phase ph+2 (vmcnt-waited next phase) ======
            if (ph <= 29) {
                const float* src = xb + (size_t)(ph + 2) * (SPH * 30);
#pragma unroll
                for (int r = 0; r < 4; ++r) {
                    int f = st4 + 256 * r;
                    int t = (ph + 2) * SPH + fs[r];
                    xr[r] = (f < 960 && t < TN) ? src[f] : 0.f;
                }
            }
            // =================== LIF2 scan(ph-2) (wave 12 lanes<35) ===================
            if (wid == 12 && lane < 35 && ph >= 2) {
                const float* cs = &c2L[(ph - 2) & 1][0][0];
                float v[SPH];
#pragma unroll
                for (int j = 0; j < SPH; ++j) v[j] = cs[j * C2W + lane];
                const int tbase = (ph - 2) * SPH;
#pragma unroll
                for (int j = 0; j < SPH; ++j) {
                    float r2 = (mem2 > 1.0f) ? 1.0f : 0.0f;
                    mem2 = 0.9f * mem2 + (v[j] + fcb) - r2;
                    if (tbase + j < TN) accO += mem2;
                }
            }
        }
        __syncthreads();
    }

    if (wid == 12 && lane < 35) out[b * 35 + lane] = accO * (1.0f / (float)TN);
}

extern "C" void kernel_launch(void* const* d_in, const int* in_sizes, int n_in,
                              void* d_out, int out_size, void* d_ws, size_t ws_size,
                              hipStream_t stream) {
    const float* x      = (const float*)d_in[0];
    const float* conv_w = (const float*)d_in[1];
    const float* conv_b = (const float*)d_in[2];
    const float* fc_w   = (const float*)d_in[3];
    const float* fc_b   = (const float*)d_in[4];
    float* out          = (float*)d_out;

    snn_fwd<<<256, 1024, 0, stream>>>(x, conv_w, conv_b, fc_w, fc_b, out);
}

// Round 3
// 146.528 us; speedup vs baseline: 1.1421x; 1.0030x over previous
//
#include <hip/hip_runtime.h>

typedef _Float16 half8 __attribute__((ext_vector_type(8)));
typedef float f32x4 __attribute__((ext_vector_type(4)));

#define SPH  32           // timesteps per phase
#define NIT  34           // 32 compute phases + 2 pipeline-drain iterations
#define SPKW 392          // spk row stride f16: 384 + 8 pad (784 B rows)
#define XTW  36           // xsT row stride (floats): 144 B rows, 16B-aligned cols
#define C2W  48           // c2L row stride (floats)
#define TN   1000

// R14: conv reads made broadcast-friendly. Model from R11-R13: phase time ~
// total per-CU LDS-pipe occupancy; conv's 336 b128 reads/phase dominate
// (24 distinct rows/inst = 384B bank work + 3-way quad conflict, ~12 cyc ea).
// Change: conv thread mapping ct -> (c = ct&15, p = ct>>4): a wave spans only
// 4 distinct xsT rows per read (16-lane broadcast groups, 4 distinct bank
// quads, conflict-free, 64B/inst). Spike K-ordering permuted to K' = p*16+c
// so conv still writes spk at half-index ct (conflict-free); A-fragments
// built with the inverse permutation (fc index = c*24+p). GEMM unchanged.
//   waves 0-5  (384 thr): conv+LIF1(ph), ONE neuron/thread (c=ct&15, p=ct>>4)
//   waves 6-11 (384 thr): FC GEMM(ph-1) ONLY (12 B-loads + 12 MFMA + store)
//   waves 12-15(256 thr): stage xsT (store ph+1, load ph+2); wave 12: LIF2
//                         scan(ph-2) + final output.
// One barrier per iteration; producer->consumer 1 barrier apart.
__global__ __launch_bounds__(1024, 4) void snn_fwd(
    const float* __restrict__ x,      // (256,1000,30)
    const float* __restrict__ conv_w, // (16,1,7)
    const float* __restrict__ conv_b, // (16)
    const float* __restrict__ fc_w,   // (35,384)
    const float* __restrict__ fc_b,   // (35)
    float* __restrict__ out)          // (256,35)
{
    __shared__ __align__(16) _Float16 spk[2][SPH][SPKW];   // 50176 B
    __shared__ __align__(16) float    xsT[2][30][XTW];     //  8640 B
    __shared__ __align__(16) float    c2L[2][SPH][C2W];    // 12288 B

    const int tid  = threadIdx.x;
    const int b    = blockIdx.x;
    const int wid  = tid >> 6;
    const int lane = tid & 63;

    // ---------- conv setup (wid<6): c-fast mapping for 4-row wave reads ----------
    const int ct = tid;              // 0..383 when wid<6
    const int c  = ct & 15;
    const int p  = ct >> 4;
    float wk[7];
    float cb = 0.f;
    if (wid < 6) {
#pragma unroll
        for (int k = 0; k < 7; ++k) wk[k] = conv_w[c * 7 + k];
        cb = conv_b[c];
    }

    // ---------- FC setup (wid 6..11): g=(wid-6): m=g>>1 (M-tile), tb=g&1 ----------
    const int g  = wid - 6;
    const int m  = g >> 1;
    const int tb = g & 1;
    const int nL = lane & 15;        // B col (t_local); C col
    const int q  = lane >> 4;        // quad: k = q*8 + j
    half8 A[12];
    if (wid >= 6 && wid < 12) {
        const int o = m * 16 + nL;
#pragma unroll
        for (int kt = 0; kt < 12; ++kt) {
            half8 a;
#pragma unroll
            for (int j = 0; j < 8; ++j) {
                int Kp = kt * 32 + q * 8 + j;    // permuted K index (p*16+c)
                int Kc = Kp & 15;                 // channel
                int Kq = Kp >> 4;                 // position
                a[j] = (o < 35) ? (_Float16)fc_w[o * 384 + Kc * 24 + Kq]
                                : (_Float16)0.f;
            }
            A[kt] = a;
        }
    }

    // ---------- stage/scan setup (wid>=12) ----------
    const int st4 = tid - 768;       // 0..255
    int fs[4], fl[4];                // f = st4+256r -> s=f/30, l=f%30 (hoisted)
    if (wid >= 12) {
#pragma unroll
        for (int r = 0; r < 4; ++r) {
            int f = st4 + 256 * r;   // 0..1023
            fs[r] = f / 30;
            fl[r] = f % 30;
        }
    }
    const float fcb = (wid == 12 && lane < 35) ? fc_b[lane] : 0.f;

    // ---------- state ----------
    float m1 = 0.f, sp = 0.f;        // LIF1 (one neuron)
    float mem2 = 0.f, accO = 0.f;    // LIF2 (wave12 lanes<35)
    float xr[4];                     // staging regs (wid>=12), data phase ph+1

    const float* xb = x + (size_t)b * (TN * 30);

    // ---------- prologue (wid>=12): stage xsT[0]; issue loads for data phase 1 ----------
    if (wid >= 12) {
#pragma unroll
        for (int r = 0; r < 4; ++r) {
            int f = st4 + 256 * r;
            if (f < 960) xsT[0][fl[r]][fs[r]] = xb[f];     // t < 32 < TN
        }
#pragma unroll
        for (int r = 0; r < 4; ++r) {
            int f = st4 + 256 * r;
            xr[r] = (f < 960) ? xb[960 + f] : 0.f;         // t < 64 < TN
        }
    }
    __syncthreads();

#pragma unroll 1
    for (int ph = 0; ph < NIT; ++ph) {
        if (wid < 6) {
            // =================== conv+LIF1(ph): 4 timesteps per iter ===================
            if (ph < 32) {
                const float* xcol = &xsT[ph & 1][p][0];
                unsigned short* sdst = (unsigned short*)&spk[ph & 1][0][ct];
#pragma unroll 2
                for (int s0 = 0; s0 < SPH; s0 += 4) {
                    f32x4 xv[7];
#pragma unroll
                    for (int k = 0; k < 7; ++k)
                        xv[k] = *(const f32x4*)(xcol + k * XTW + s0);
                    float cc[4];
#pragma unroll
                    for (int dt = 0; dt < 4; ++dt) cc[dt] = cb;
#pragma unroll
                    for (int k = 0; k < 7; ++k) {
#pragma unroll
                        for (int dt = 0; dt < 4; ++dt)
                            cc[dt] = fmaf(wk[k], xv[k][dt], cc[dt]);
                    }
#pragma unroll
                    for (int dt = 0; dt < 4; ++dt) {
                        m1 = fmaf(0.9f, m1, cc[dt] - sp);
                        sp = (m1 > 1.0f) ? 1.0f : 0.0f;
                        sdst[(s0 + dt) * SPKW] =
                            (m1 > 1.0f) ? (unsigned short)0x3C00u : (unsigned short)0u;
                    }
                }
            }
        } else if (wid < 12) {
            // =================== GEMM(ph-1): this wave's (m, tb) ===================
            if (ph >= 1 && ph <= 32) {
                const _Float16* sb = &spk[(ph - 1) & 1][0][0];
                half8 B[12];
#pragma unroll
                for (int kt = 0; kt < 12; ++kt)
                    B[kt] = *(const half8*)(sb + (tb * 16 + nL) * SPKW + kt * 32 + q * 8);
                f32x4 acc = {0.f, 0.f, 0.f, 0.f};
#pragma unroll
                for (int kt = 0; kt < 12; ++kt)
                    acc = __builtin_amdgcn_mfma_f32_16x16x32_f16(A[kt], B[kt], acc, 0, 0, 0);
                // C/D: col = lane&15 (t_local), row = q*4+i (o_local)
                float* cd = &c2L[(ph - 1) & 1][0][0];
                *(f32x4*)(cd + (tb * 16 + nL) * C2W + m * 16 + q * 4) = acc;
            }
        } else {
            // ====== staging store (data ph+1, loaded a full phase ago) ======
            if (ph <= 30) {
                float* dst = &xsT[(ph + 1) & 1][0][0];
#pragma unroll
                for (int r = 0; r < 4; ++r) {
                    int f = st4 + 256 * r;
                    if (f < 960) dst[fl[r] * XTW + fs[r]] = xr[r];
                }
            }
            // ====== staging loads for data phase ph+2 (vmcnt-waited next phase) ======
            if (ph <= 29) {
                const float* src = xb + (size_t)(ph + 2) * (SPH * 30);
#pragma unroll
                for (int r = 0; r < 4; ++r) {
                    int f = st4 + 256 * r;
                    int t = (ph + 2) * SPH + fs[r];
                    xr[r] = (f < 960 && t < TN) ? src[f] : 0.f;
                }
            }
            // =================== LIF2 scan(ph-2) (wave 12 lanes<35) ===================
            if (wid == 12 && lane < 35 && ph >= 2) {
                const float* cs = &c2L[(ph - 2) & 1][0][0];
                float v[SPH];
#pragma unroll
                for (int j = 0; j < SPH; ++j) v[j] = cs[j * C2W + lane];
                const int tbase = (ph - 2) * SPH;
#pragma unroll
                for (int j = 0; j < SPH; ++j) {
                    float r2 = (mem2 > 1.0f) ? 1.0f : 0.0f;
                    mem2 = 0.9f * mem2 + (v[j] + fcb) - r2;
                    if (tbase + j < TN) accO += mem2;
                }
            }
        }
        __syncthreads();
    }

    if (wid == 12 && lane < 35) out[b * 35 + lane] = accO * (1.0f / (float)TN);
}

extern "C" void kernel_launch(void* const* d_in, const int* in_sizes, int n_in,
                              void* d_out, int out_size, void* d_ws, size_t ws_size,
                              hipStream_t stream) {
    const float* x      = (const float*)d_in[0];
    const float* conv_w = (const float*)d_in[1];
    const float* conv_b = (const float*)d_in[2];
    const float* fc_w   = (const float*)d_in[3];
    const float* fc_b   = (const float*)d_in[4];
    float* out          = (float*)d_out;

    snn_fwd<<<256, 1024, 0, stream>>>(x, conv_w, conv_b, fc_w, fc_b, out);
}